// Round 7
// baseline (414.471 us; speedup 1.0000x reference)
//
#include <hip/hip_runtime.h>
#include <stdint.h>

// PointNet SA via MFMA, v5: software-pipelined tiles + pre-transposed packed features.
// fp32 emulated as bf16 hi/lo (3-mfma: Ah*Bh + Ah*Bl + Al*Bh). Activations in LDS as
// packed dwords (hi16|lo16 per channel), swizzled; unpack to frags via v_perm.
// 4 tiles(64 pts)/block, next-tile gather issued early into regs, committed after stage-1.

namespace {
constexpr int kB = 4, kN = 16384, kC = 103, kP = 2048, kS = 32;
constexpr int TPB = 4;                          // tiles per block
constexpr int NBLK = (kB * kP * kS) / 64 / TPB; // 1024

using short8 = __attribute__((ext_vector_type(8))) short;
using f32x4  = __attribute__((ext_vector_type(4))) float;

// d_ws: [0, 208KB) weight hi/lo planes (shorts) | [256KB, +33.5MB) featT packed dwords
constexpr int WG_HI = 0,     WG_LO = 8192;     // 64 x 128
constexpr int W1_HI = 16384, W1_LO = 20480;    // 64 x 64
constexpr int W2_HI = 24576, W2_LO = 32768;    // 128 x 64
constexpr int W3_HI = 40960, W3_LO = 73728;    // 256 x 128
constexpr size_t FEATT_OFF   = 262144;                       // bytes
constexpr size_t FEATT_BYTES = (size_t)kB * kN * 128 * 4;    // 33.55 MB
constexpr size_t WS_NEED     = FEATT_OFF + FEATT_BYTES;

// pack f32 -> (hi_bf16<<16)|lo_bf16, both RNE (same rounding chain as v4: absmax preserved)
__device__ __forceinline__ uint32_t pack2(float v) {
    uint32_t u  = __float_as_uint(v);
    uint32_t t  = u + 0x7fffu + ((u >> 16) & 1u);
    uint32_t hi = t & 0xffff0000u;
    float    r  = v - __uint_as_float(hi);
    uint32_t ru = __float_as_uint(r);
    uint32_t t2 = ru + 0x7fffu + ((ru >> 16) & 1u);
    return hi | (t2 >> 16);
}
__device__ __forceinline__ float unpack_f32(uint32_t d) {
    return __uint_as_float(d & 0xffff0000u) + __uint_as_float(d << 16);
}

__global__ void copy_newxyz(const float* __restrict__ src, float* __restrict__ dst, int n) {
    int i = blockIdx.x * blockDim.x + threadIdx.x;
    if (i < n) dst[i] = src[i];
}

__global__ void prep_weights(const float* __restrict__ Wg, const float* __restrict__ W1,
                             const float* __restrict__ W2, const float* __restrict__ W3,
                             short* __restrict__ ws) {
    int i = blockIdx.x * blockDim.x + threadIdx.x;
    if (i >= 53248) return;
    float w; int hi, lo, j;
    if (i < 8192)       { j = i;         int o = j >> 7, c = j & 127; w = (c < 106) ? Wg[o * 106 + c] : 0.f; hi = WG_HI; lo = WG_LO; }
    else if (i < 12288) { j = i - 8192;  int o = j >> 6, c = j & 63;  w = W1[o * 64 + c];  hi = W1_HI; lo = W1_LO; }
    else if (i < 20480) { j = i - 12288; int o = j >> 6, c = j & 63;  w = W2[o * 64 + c];  hi = W2_HI; lo = W2_LO; }
    else                { j = i - 20480; int o = j >> 7, c = j & 127; w = W3[o * 128 + c]; hi = W3_HI; lo = W3_LO; }
    uint32_t p = pack2(w);
    ws[hi + j] = (short)(p >> 16);
    ws[lo + j] = (short)(p & 0xffff);
}

// featT[b][n][col]: col 0-2 placeholder(0), 3..105 = pack(features[b][col-3][n]), 106-127 = 0
__global__ __launch_bounds__(512) void prep_featT(const float* __restrict__ f, uint32_t* __restrict__ ft) {
    __shared__ float tile[kC][65];
    const int bb = blockIdx.x >> 8;              // 256 slabs of 64 n per batch
    const int n0 = (blockIdx.x & 255) * 64;
    const int tid = threadIdx.x;
    const int cr = tid >> 6, ln = tid & 63;
    const float* fb = f + (size_t)bb * kC * kN;
    for (int c = cr; c < kC; c += 8) tile[c][ln] = fb[(size_t)c * kN + n0 + ln];
    __syncthreads();
    const int np = tid >> 3, gc = tid & 7;
    uint32_t* row = ft + ((size_t)bb * kN + n0 + np) * 128;
    #pragma unroll
    for (int k = 0; k < 4; ++k) {
        uint32_t w[4];
        #pragma unroll
        for (int e = 0; e < 4; ++e) {
            int col = 4 * gc + 32 * k + e;
            float v = (col >= 3 && col < 106) ? tile[col - 3][np] : 0.f;
            w[e] = pack2(v);
        }
        *(uint4*)(row + 4 * gc + 32 * k) = make_uint4(w[0], w[1], w[2], w[3]);
    }
}

// B-frag pair from packed LDS row (swizzled at 16B granularity)
__device__ __forceinline__ void bfrag(const uint32_t* row, int k0, int swz, short8& h, short8& l) {
    uint4 d0 = *(const uint4*)(row + (k0 ^ swz));
    uint4 d1 = *(const uint4*)(row + ((k0 + 4) ^ swz));
    union { uint32_t u[4]; short8 s; } H, L;
    H.u[0] = __builtin_amdgcn_perm(d0.y, d0.x, 0x07060302u);
    H.u[1] = __builtin_amdgcn_perm(d0.w, d0.z, 0x07060302u);
    H.u[2] = __builtin_amdgcn_perm(d1.y, d1.x, 0x07060302u);
    H.u[3] = __builtin_amdgcn_perm(d1.w, d1.z, 0x07060302u);
    L.u[0] = __builtin_amdgcn_perm(d0.y, d0.x, 0x05040100u);
    L.u[1] = __builtin_amdgcn_perm(d0.w, d0.z, 0x05040100u);
    L.u[2] = __builtin_amdgcn_perm(d1.y, d1.x, 0x05040100u);
    L.u[3] = __builtin_amdgcn_perm(d1.w, d1.z, 0x05040100u);
    h = H.s; l = L.s;
}

// A: m=lane&15 (W row), k=8*(lane>>4)+j; B: n=lane&15 (point), same k; D: n=lane&15, m=4*(lane>>4)+r
template<int NOT, int NPT, int KT, int LDC>
__device__ __forceinline__ void gemm_ps(
    const uint32_t* __restrict__ x, const short* __restrict__ wh, const short* __restrict__ wl,
    const float* __restrict__ bias, int ot0, int pt0t, int lane, f32x4 (&acc)[NOT][NPT])
{
    const int q = lane >> 4, n16 = lane & 15;
    #pragma unroll
    for (int i = 0; i < NOT; ++i) {
        const f32x4 binit = *(const f32x4*)(bias + (ot0 + i) * 16 + 4 * q);
        #pragma unroll
        for (int j = 0; j < NPT; ++j) acc[i][j] = binit;
    }
    #pragma unroll
    for (int kt = 0; kt < KT; ++kt) {
        const int k0 = kt * 32 + q * 8;
        short8 bh[NPT], bl[NPT];
        #pragma unroll
        for (int j = 0; j < NPT; ++j) {
            const int p = (pt0t + j) * 16 + n16;
            bfrag(x + p * LDC, k0, (p & 15) << 2, bh[j], bl[j]);
        }
        #pragma unroll
        for (int i = 0; i < NOT; ++i) {
            const size_t we = (size_t)((ot0 + i) * 16 + n16) * (KT * 32) + k0;
            const short8 ah = *(const short8*)(wh + we);
            const short8 al = *(const short8*)(wl + we);
            #pragma unroll
            for (int j = 0; j < NPT; ++j) {
                acc[i][j] = __builtin_amdgcn_mfma_f32_16x16x32_bf16(ah, bh[j], acc[i][j], 0, 0, 0);
                acc[i][j] = __builtin_amdgcn_mfma_f32_16x16x32_bf16(ah, bl[j], acc[i][j], 0, 0, 0);
                acc[i][j] = __builtin_amdgcn_mfma_f32_16x16x32_bf16(al, bh[j], acc[i][j], 0, 0, 0);
            }
        }
    }
}

template<int NOT, int NPT, bool GATE, int LDCO>
__device__ __forceinline__ void store_ps(
    f32x4 (&acc)[NOT][NPT], uint32_t* __restrict__ out, const uint32_t* __restrict__ nf,
    int ot0, int pt0t, int lane)
{
    const int q = lane >> 4, n16 = lane & 15;
    #pragma unroll
    for (int i = 0; i < NOT; ++i) {
        const int ob = (ot0 + i) * 16 + 4 * q;
        #pragma unroll
        for (int j = 0; j < NPT; ++j) {
            const int p = (pt0t + j) * 16 + n16;
            const int swz = (p & 15) << 2;
            uint32_t pk[4];
            uint4 bd;
            if (GATE) bd = *(const uint4*)(nf + p * 128 + (ob ^ swz));
            #pragma unroll
            for (int r = 0; r < 4; ++r) {
                float v = acc[i][j][r];
                if (GATE) {
                    const uint32_t d = (r == 0) ? bd.x : (r == 1) ? bd.y : (r == 2) ? bd.z : bd.w;
                    const float base = unpack_f32(d);
                    v = fmaf(base, v, base);           // base*(1+w)
                } else {
                    v = fmaxf(v, 0.f);
                }
                pk[r] = pack2(v);
            }
            *(uint4*)(out + p * LDCO + (ob ^ swz)) = make_uint4(pk[0], pk[1], pk[2], pk[3]);
        }
    }
}

struct Pref { uint32_t nf[16]; float xr[3]; float nxr[3]; };

// Issue-phase: start loads (raw values only; no math on loaded data -> no forced waits)
template<bool DENSE>
__device__ __forceinline__ void issue_pref(
    int n, int pt, int b, int gc, const uint32_t* __restrict__ ftb,
    const float* __restrict__ fbase, const float* __restrict__ xyz,
    const float* __restrict__ new_xyz, Pref& P)
{
    if (DENSE) {
        const uint32_t* row = ftb + (size_t)n * 128;
        #pragma unroll
        for (int k = 0; k < 4; ++k) {
            uint4 v = *(const uint4*)(row + 4 * gc + 32 * k);
            P.nf[4 * k + 0] = v.x; P.nf[4 * k + 1] = v.y;
            P.nf[4 * k + 2] = v.z; P.nf[4 * k + 3] = v.w;
        }
    } else {
        #pragma unroll
        for (int k = 0; k < 4; ++k)
            #pragma unroll
            for (int e = 0; e < 4; ++e) {
                const int col = 4 * gc + 32 * k + e;
                float v = 0.f;
                if (col >= 3 && col < 106) v = fbase[(size_t)(col - 3) * kN + n];
                P.nf[4 * k + e] = __float_as_uint(v);
            }
    }
    if (gc == 0) {
        const float* xp = xyz + ((size_t)b * kN + n) * 3;
        const int pp = (pt >> 5) & (kP - 1);
        const float* np = new_xyz + ((size_t)b * kP + pp) * 3;
        #pragma unroll
        for (int c = 0; c < 3; ++c) { P.xr[c] = xp[c]; P.nxr[c] = np[c]; }
    }
}

// Commit-phase: pack (sparse) / merge xyz, write swizzled b128s to NF
template<bool DENSE>
__device__ __forceinline__ void commit_NF(uint32_t* __restrict__ NF, const Pref& P, int gp, int gc) {
    uint32_t w[16];
    #pragma unroll
    for (int i = 0; i < 16; ++i)
        w[i] = DENSE ? P.nf[i] : pack2(__uint_as_float(P.nf[i]));
    if (gc == 0) {
        #pragma unroll
        for (int c = 0; c < 3; ++c) w[c] = pack2(P.xr[c] - P.nxr[c]);
    }
    const int swz = (gp & 15) << 2;
    uint32_t* row = NF + gp * 128;
    #pragma unroll
    for (int k = 0; k < 4; ++k)
        *(uint4*)(row + ((4 * gc + 32 * k) ^ swz)) =
            make_uint4(w[4 * k], w[4 * k + 1], w[4 * k + 2], w[4 * k + 3]);
}

template<bool DENSE>
__global__ __launch_bounds__(512, 4) void pointnet_sa(
    const float* __restrict__ xyz, const float* __restrict__ features,
    const float* __restrict__ new_xyz, const int* __restrict__ idx,
    const short* __restrict__ wsw, const uint32_t* __restrict__ featT,
    const float* __restrict__ bg, const float* __restrict__ b1,
    const float* __restrict__ b2, const float* __restrict__ b3,
    float* __restrict__ out_pooled)  // (B, 256, P)
{
    __shared__ uint32_t smem[16384];             // 64 KB
    uint32_t* NF = smem;                         // [64][128]
    uint32_t* X0 = smem + 8192;                  // [64][64]
    uint32_t* X1 = smem + 12288;                 // [64][64]
    uint32_t* X2 = X0;                           // [64][128] alias over X0|X1

    const int tid = threadIdx.x, lane = tid & 63, wave = tid >> 6;
    const int q = lane >> 4, n16 = lane & 15;
    const int gp = tid >> 3, gc = tid & 7;       // gather roles: point, col-group
    const int base = blockIdx.x * (64 * TPB);
    const int b = base >> 16;
    const float* fbase = features + (size_t)b * kC * kN;
    const uint32_t* ftb = DENSE ? (featT + (size_t)b * kN * 128) : nullptr;

    Pref P;
    // prologue: tile 0 synchronous; prefetch idx for tile 1
    int n_cur = idx[base + gp];
    int n_nxt = (TPB > 1) ? idx[base + 64 + gp] : 0;
    issue_pref<DENSE>(n_cur, base + gp, b, gc, ftb, fbase, xyz, new_xyz, P);
    commit_NF<DENSE>(NF, P, gp, gc);
    __syncthreads();

    for (int t = 0; t < TPB; ++t) {
        const int ptb = base + t * 64;
        if (t + 1 < TPB)
            issue_pref<DENSE>(n_nxt, ptb + 64 + gp, b, gc, ftb, fbase, xyz, new_xyz, P);
        int n_n2 = 0;
        if (t + 2 < TPB) n_n2 = idx[ptb + 128 + gp];

        // stage g: w = Wg*nf + bg ; x0 = base*(1+w)
        {
            f32x4 a[1][2];
            gemm_ps<1, 2, 4, 128>(NF, wsw + WG_HI, wsw + WG_LO, bg, wave & 3, 2 * (wave >> 2), lane, a);
            store_ps<1, 2, true, 64>(a, X0, NF, wave & 3, 2 * (wave >> 2), lane);
        }
        __syncthreads();                                   // B1: NF reads + X0 writes done
        // stage 1
        {
            f32x4 a[1][2];
            gemm_ps<1, 2, 2, 64>(X0, wsw + W1_HI, wsw + W1_LO, b1, wave & 3, 2 * (wave >> 2), lane, a);
            store_ps<1, 2, false, 64>(a, X1, nullptr, wave & 3, 2 * (wave >> 2), lane);
        }
        if (t + 1 < TPB) commit_NF<DENSE>(NF, P, gp, gc);  // NF dead; hides load latency
        __syncthreads();                                   // B2
        // stage 2 (gemm, then barrier, then store over X0|X1)
        f32x4 a2[2][2];
        gemm_ps<2, 2, 2, 64>(X1, wsw + W2_HI, wsw + W2_LO, b2, 2 * (wave & 3), 2 * (wave >> 2), lane, a2);
        __syncthreads();                                   // B3: X1 reads done
        store_ps<2, 2, false, 128>(a2, X2, nullptr, 2 * (wave & 3), 2 * (wave >> 2), lane);
        __syncthreads();                                   // B3b: X2 visible
        // stage 3 + pool
        {
            f32x4 a3[2][4];
            gemm_ps<2, 4, 4, 128>(X2, wsw + W3_HI, wsw + W3_LO, b3, 2 * wave, 0, lane, a3);
            #pragma unroll
            for (int i = 0; i < 2; ++i)
                #pragma unroll
                for (int sg = 0; sg < 2; ++sg)
                    #pragma unroll
                    for (int r = 0; r < 4; ++r) {
                        float a = fmaxf(a3[i][2 * sg][r], a3[i][2 * sg + 1][r]);
                        a = fmaxf(a, __shfl_xor(a, 1, 16));
                        a = fmaxf(a, __shfl_xor(a, 2, 16));
                        a = fmaxf(a, __shfl_xor(a, 4, 16));
                        a = fmaxf(a, __shfl_xor(a, 8, 16));
                        a = fmaxf(a, 0.f);
                        if (n16 == 0) {
                            const int o = (2 * wave + i) * 16 + 4 * q + r;
                            const int g = (ptb >> 5) + sg;          // flat b*P + p
                            out_pooled[((size_t)(g >> 11) * 256 + o) * kP + (g & (kP - 1))] = a;
                        }
                    }
        }
        __syncthreads();                                   // B4: X2 reads done
        n_nxt = n_n2;
    }
}
}  // namespace

extern "C" void kernel_launch(void* const* d_in, const int* in_sizes, int n_in,
                              void* d_out, int out_size, void* d_ws, size_t ws_size,
                              hipStream_t stream) {
    const float* xyz      = (const float*)d_in[0];
    const float* features = (const float*)d_in[1];
    const float* new_xyz  = (const float*)d_in[2];
    const int*   idx      = (const int*)d_in[3];
    const float* Wg = (const float*)d_in[4];
    const float* bg = (const float*)d_in[5];
    const float* W1 = (const float*)d_in[6];
    const float* b1 = (const float*)d_in[7];
    const float* W2 = (const float*)d_in[8];
    const float* b2 = (const float*)d_in[9];
    const float* W3 = (const float*)d_in[10];
    const float* b3 = (const float*)d_in[11];
    float* out = (float*)d_out;
    short* wsw = (short*)d_ws;
    uint32_t* featT = (uint32_t*)((char*)d_ws + FEATT_OFF);

    const int nxyz = kB * kP * 3;
    copy_newxyz<<<(nxyz + 255) / 256, 256, 0, stream>>>(new_xyz, out, nxyz);
    prep_weights<<<(53248 + 255) / 256, 256, 0, stream>>>(Wg, W1, W2, W3, wsw);

    float* pooled = out + nxyz;
    if (ws_size >= WS_NEED) {
        prep_featT<<<kB * (kN / 64), 512, 0, stream>>>(features, featT);
        pointnet_sa<true><<<NBLK, 512, 0, stream>>>(
            xyz, features, new_xyz, idx, wsw, featT, bg, b1, b2, b3, pooled);
    } else {
        pointnet_sa<false><<<NBLK, 512, 0, stream>>>(
            xyz, features, new_xyz, idx, wsw, nullptr, bg, b1, b2, b3, pooled);
    }
}

// Round 8
// 185.924 us; speedup vs baseline: 2.2293x; 2.2293x over previous
//
#include <hip/hip_runtime.h>
#include <stdint.h>

// PointNet SA via MFMA, v6 = v4 structure + dense vectorized gather.
// fp32 emulated as bf16 hi/lo split: D = Ah*Bh + Ah*Bl + Al*Bh (3 mfma).
// Features pre-transposed once to hi/lo short planes ftH/ftL[b][n][128]; gather is
// coalesced uint4 loads -> swizzled ds_write_b128 (kills v4's 64-way write conflicts
// and the 27M scattered 4B loads). No register pipelining (v5's spill lesson).

namespace {
constexpr int kB = 4, kN = 16384, kC = 103, kP = 2048, kS = 32;

using short8 = __attribute__((ext_vector_type(8))) short;
using short4 = __attribute__((ext_vector_type(4))) short;
using f32x4  = __attribute__((ext_vector_type(4))) float;

// d_ws: [0,208KB) weight hi/lo planes (shorts) | [256KB) ftH | ftL (each 16.78MB)
constexpr int WG_HI = 0,     WG_LO = 8192;     // 64 x 128
constexpr int W1_HI = 16384, W1_LO = 20480;    // 64 x 64
constexpr int W2_HI = 24576, W2_LO = 32768;    // 128 x 64
constexpr int W3_HI = 40960, W3_LO = 73728;    // 256 x 128
constexpr size_t FT_OFF    = 262144;                         // bytes
constexpr size_t FT_SHORTS = (size_t)kB * kN * 128;          // per plane
constexpr size_t WS_NEED   = FT_OFF + 2 * FT_SHORTS * 2;     // ~33.8 MB

__device__ __forceinline__ unsigned short f2bf(float x) {
    unsigned u = __float_as_uint(x);
    u += 0x7fffu + ((u >> 16) & 1u);           // RNE
    return (unsigned short)(u >> 16);
}
__device__ __forceinline__ float bf2f(unsigned short h) {
    return __uint_as_float((unsigned)h << 16);
}

__global__ void copy_newxyz(const float* __restrict__ src, float* __restrict__ dst, int n) {
    int i = blockIdx.x * blockDim.x + threadIdx.x;
    if (i < n) dst[i] = src[i];
}

__global__ void prep_weights(const float* __restrict__ Wg, const float* __restrict__ W1,
                             const float* __restrict__ W2, const float* __restrict__ W3,
                             short* __restrict__ ws) {
    int i = blockIdx.x * blockDim.x + threadIdx.x;
    if (i >= 53248) return;
    float w; int hi, lo, j;
    if (i < 8192)       { j = i;         int o = j >> 7, c = j & 127; w = (c < 106) ? Wg[o * 106 + c] : 0.f; hi = WG_HI; lo = WG_LO; }
    else if (i < 12288) { j = i - 8192;  int o = j >> 6, c = j & 63;  w = W1[o * 64 + c];  hi = W1_HI; lo = W1_LO; }
    else if (i < 20480) { j = i - 12288; int o = j >> 6, c = j & 63;  w = W2[o * 64 + c];  hi = W2_HI; lo = W2_LO; }
    else                { j = i - 20480; int o = j >> 7, c = j & 127; w = W3[o * 128 + c]; hi = W3_HI; lo = W3_LO; }
    unsigned short h = f2bf(w);
    ws[hi + j] = (short)h;
    ws[lo + j] = (short)f2bf(w - bf2f(h));
}

// ftH/ftL[b][n][col]: col 0-2 = 0 (xyz placeholder), 3..105 = features[b][col-3][n], rest 0
__global__ __launch_bounds__(512) void prep_feat(const float* __restrict__ f,
                                                 short* __restrict__ ftH, short* __restrict__ ftL) {
    __shared__ float tile[kC][65];
    const int bb = blockIdx.x >> 8;              // 256 slabs of 64 n per batch
    const int n0 = (blockIdx.x & 255) * 64;
    const int tid = threadIdx.x;
    for (int c = tid >> 6; c < kC; c += 8)
        tile[c][tid & 63] = f[((size_t)bb * kC + c) * kN + n0 + (tid & 63)];
    __syncthreads();
    const int np = tid >> 3, gc = tid & 7;
    short* rH = ftH + ((size_t)bb * kN + n0 + np) * 128;
    short* rL = ftL + ((size_t)bb * kN + n0 + np) * 128;
    #pragma unroll
    for (int kk = 0; kk < 2; ++kk) {
        const int chunk = gc + 8 * kk;
        union { uint4 u; short s[8]; } H, L;
        #pragma unroll
        for (int e = 0; e < 8; ++e) {
            const int col = chunk * 8 + e;
            float v = (col >= 3 && col < 106) ? tile[col - 3][np] : 0.f;
            unsigned short hh = f2bf(v);
            H.s[e] = (short)hh;
            L.s[e] = (short)f2bf(v - bf2f(hh));
        }
        *(uint4*)(rH + chunk * 8) = H.u;
        *(uint4*)(rL + chunk * 8) = L.u;
    }
}

// A: m=lane&15 (W row), k=8*(lane>>4)+j; B: n=lane&15 (point), same k; D: n=lane&15, m=4*(lane>>4)+r
template<int NOT, int NPT, int KT, int LDC>
__device__ __forceinline__ void gemm_stage(
    const short* __restrict__ xh, const short* __restrict__ xl,
    const short* __restrict__ wh, const short* __restrict__ wl,
    const float* __restrict__ bias,
    int ot0, int pt0t, int lane, f32x4 (&acc)[NOT][NPT])
{
    const int q = lane >> 4, n16 = lane & 15;
    #pragma unroll
    for (int i = 0; i < NOT; ++i) {
        const f32x4 binit = *(const f32x4*)(bias + (ot0 + i) * 16 + 4 * q);
        #pragma unroll
        for (int j = 0; j < NPT; ++j) acc[i][j] = binit;
    }
    #pragma unroll
    for (int kt = 0; kt < KT; ++kt) {
        const int k0 = kt * 32 + q * 8;
        short8 bh[NPT], bl[NPT];
        #pragma unroll
        for (int j = 0; j < NPT; ++j) {
            const int p = (pt0t + j) * 16 + n16;
            const int e = p * LDC + (k0 ^ ((p & 7) << 3));
            bh[j] = *(const short8*)(xh + e);
            bl[j] = *(const short8*)(xl + e);
        }
        #pragma unroll
        for (int i = 0; i < NOT; ++i) {
            const size_t we = (size_t)((ot0 + i) * 16 + n16) * (KT * 32) + k0;
            const short8 ah = *(const short8*)(wh + we);
            const short8 al = *(const short8*)(wl + we);
            #pragma unroll
            for (int j = 0; j < NPT; ++j) {
                acc[i][j] = __builtin_amdgcn_mfma_f32_16x16x32_bf16(ah, bh[j], acc[i][j], 0, 0, 0);
                acc[i][j] = __builtin_amdgcn_mfma_f32_16x16x32_bf16(ah, bl[j], acc[i][j], 0, 0, 0);
                acc[i][j] = __builtin_amdgcn_mfma_f32_16x16x32_bf16(al, bh[j], acc[i][j], 0, 0, 0);
            }
        }
    }
}

template<int NOT, int NPT, bool GATE, int LDCO>
__device__ __forceinline__ void store_act(
    f32x4 (&acc)[NOT][NPT], short* __restrict__ oh, short* __restrict__ ol,
    const short* __restrict__ nfh, const short* __restrict__ nfl,
    int ot0, int pt0t, int lane)
{
    const int q = lane >> 4, n16 = lane & 15;
    #pragma unroll
    for (int i = 0; i < NOT; ++i) {
        const int ob = (ot0 + i) * 16 + 4 * q;
        #pragma unroll
        for (int j = 0; j < NPT; ++j) {
            const int p = (pt0t + j) * 16 + n16;
            const int cs = ob ^ ((p & 7) << 3);
            float v[4];
            #pragma unroll
            for (int r = 0; r < 4; ++r) v[r] = acc[i][j][r];
            if (GATE) {
                const short4 h4 = *(const short4*)(nfh + p * 128 + cs);
                const short4 l4 = *(const short4*)(nfl + p * 128 + cs);
                #pragma unroll
                for (int r = 0; r < 4; ++r) {
                    const float base = bf2f((unsigned short)h4[r]) + bf2f((unsigned short)l4[r]);
                    v[r] = fmaf(base, v[r], base);      // base*(1+w)
                }
            } else {
                #pragma unroll
                for (int r = 0; r < 4; ++r) v[r] = fmaxf(v[r], 0.f);
            }
            short4 h4o, l4o;
            #pragma unroll
            for (int r = 0; r < 4; ++r) {
                const unsigned short h = f2bf(v[r]);
                h4o[r] = (short)h;
                l4o[r] = (short)f2bf(v[r] - bf2f(h));
            }
            *(short4*)(oh + p * LDCO + cs) = h4o;
            *(short4*)(ol + p * LDCO + cs) = l4o;
        }
    }
}

template<bool DENSE>
__global__ __launch_bounds__(512, 4) void pointnet_sa(
    const float* __restrict__ xyz, const float* __restrict__ features,
    const float* __restrict__ new_xyz, const int* __restrict__ idx,
    const short* __restrict__ ws, const short* __restrict__ ftH, const short* __restrict__ ftL,
    const float* __restrict__ bg, const float* __restrict__ b1,
    const float* __restrict__ b2, const float* __restrict__ b3,
    float* __restrict__ out_pooled)  // (B, 256, P)
{
    __shared__ short smem[32768];                  // 64 KB
    short* NFh = smem;          short* NFl = smem + 8192;    // [64][128]
    short* X0h = smem + 16384;  short* X0l = smem + 20480;   // [64][64]
    short* X1h = smem + 24576;  short* X1l = smem + 28672;   // [64][64]
    short* X2h = NFh;           short* X2l = NFl;            // alias (NF dead after stage g)

    const int tid = threadIdx.x, lane = tid & 63, wave = tid >> 6;
    const int q = lane >> 4, n16 = lane & 15;
    const int pt0 = blockIdx.x * 64;
    const int b = pt0 >> 16;                       // P*S = 65536 points per batch

    if (DENSE) {
        // ---- dense gather: 8 threads/point, 4x uint4 load + 4x swizzled b128 store ----
        const int gp = tid >> 3, gc = tid & 7;
        const int pt = pt0 + gp;
        const int n = idx[pt];
        const short* rH = ftH + ((size_t)b * kN + n) * 128;
        const short* rL = ftL + ((size_t)b * kN + n) * 128;
        uint4 hc0 = *(const uint4*)(rH + gc * 8);
        uint4 hc1 = *(const uint4*)(rH + gc * 8 + 64);
        uint4 lc0 = *(const uint4*)(rL + gc * 8);
        uint4 lc1 = *(const uint4*)(rL + gc * 8 + 64);
        if (gc == 0) {                              // merge xyz-diff into cols 0..2
            const float* xp = xyz + ((size_t)b * kN + n) * 3;
            const int pp = (pt >> 5) & (kP - 1);
            const float* np = new_xyz + ((size_t)b * kP + pp) * 3;
            union { uint4 u; short s[8]; } H, L;
            H.u = hc0; L.u = lc0;
            #pragma unroll
            for (int c = 0; c < 3; ++c) {
                const float v = xp[c] - np[c];
                const unsigned short hh = f2bf(v);
                H.s[c] = (short)hh;
                L.s[c] = (short)f2bf(v - bf2f(hh));
            }
            hc0 = H.u; lc0 = L.u;
        }
        const int sw = (gc ^ (gp & 7)) * 8;         // chunk-level XOR swizzle
        *(uint4*)(NFh + gp * 128 + sw)      = hc0;
        *(uint4*)(NFh + gp * 128 + sw + 64) = hc1;
        *(uint4*)(NFl + gp * 128 + sw)      = lc0;
        *(uint4*)(NFl + gp * 128 + sw + 64) = lc1;
    } else {
        // ---- fallback: v4 scalar gather ----
        const int p = tid & 63;
        const int cg = tid >> 6;
        const int pt = pt0 + p;
        const int n = idx[pt];
        const int pp = (pt >> 5) & (kP - 1);
        const float* fb = features + (size_t)b * kC * kN + n;
        const float* xp = xyz + ((size_t)b * kN + n) * 3;
        const float* np = new_xyz + ((size_t)b * kP + pp) * 3;
        for (int c = cg; c < 128; c += 8) {
            float v;
            if (c < 3)        v = xp[c] - np[c];
            else if (c < 106) v = fb[(size_t)(c - 3) * kN];
            else              v = 0.f;
            const unsigned short h = f2bf(v);
            const int cs = c ^ ((p & 7) << 3);
            NFh[p * 128 + cs] = (short)h;
            NFl[p * 128 + cs] = (short)f2bf(v - bf2f(h));
        }
    }
    __syncthreads();

    // ---- stage g: w = Wg*nf + bg ; x0 = nf[:64]*(1+w) ----
    {
        f32x4 acc[1][2];
        gemm_stage<1, 2, 4, 128>(NFh, NFl, ws + WG_HI, ws + WG_LO, bg,
                                 wave & 3, 2 * (wave >> 2), lane, acc);
        store_act<1, 2, true, 64>(acc, X0h, X0l, NFh, NFl, wave & 3, 2 * (wave >> 2), lane);
    }
    __syncthreads();

    // ---- stage 1 ----
    {
        f32x4 acc[1][2];
        gemm_stage<1, 2, 2, 64>(X0h, X0l, ws + W1_HI, ws + W1_LO, b1,
                                wave & 3, 2 * (wave >> 2), lane, acc);
        store_act<1, 2, false, 64>(acc, X1h, X1l, nullptr, nullptr, wave & 3, 2 * (wave >> 2), lane);
    }
    __syncthreads();

    // ---- stage 2 ----
    {
        f32x4 acc[2][2];
        gemm_stage<2, 2, 2, 64>(X1h, X1l, ws + W2_HI, ws + W2_LO, b2,
                                2 * (wave & 3), 2 * (wave >> 2), lane, acc);
        store_act<2, 2, false, 128>(acc, X2h, X2l, nullptr, nullptr, 2 * (wave & 3), 2 * (wave >> 2), lane);
    }
    __syncthreads();

    // ---- stage 3 + max-pool over s (32 pts = 2 p-tiles) ----
    {
        f32x4 acc[2][4];
        gemm_stage<2, 4, 4, 128>(X2h, X2l, ws + W3_HI, ws + W3_LO, b3,
                                 2 * wave, 0, lane, acc);
        #pragma unroll
        for (int i = 0; i < 2; ++i) {
            #pragma unroll
            for (int sg = 0; sg < 2; ++sg) {
                #pragma unroll
                for (int r = 0; r < 4; ++r) {
                    float a = fmaxf(acc[i][2 * sg][r], acc[i][2 * sg + 1][r]);
                    a = fmaxf(a, __shfl_xor(a, 1, 16));
                    a = fmaxf(a, __shfl_xor(a, 2, 16));
                    a = fmaxf(a, __shfl_xor(a, 4, 16));
                    a = fmaxf(a, __shfl_xor(a, 8, 16));
                    a = fmaxf(a, 0.f);
                    if (n16 == 0) {
                        const int o = (2 * wave + i) * 16 + 4 * q + r;
                        const int g = (pt0 >> 5) + sg;                 // flat b*P + p
                        out_pooled[((size_t)(g >> 11) * 256 + o) * kP + (g & (kP - 1))] = a;
                    }
                }
            }
        }
    }
}
}  // namespace

extern "C" void kernel_launch(void* const* d_in, const int* in_sizes, int n_in,
                              void* d_out, int out_size, void* d_ws, size_t ws_size,
                              hipStream_t stream) {
    const float* xyz      = (const float*)d_in[0];
    const float* features = (const float*)d_in[1];
    const float* new_xyz  = (const float*)d_in[2];
    const int*   idx      = (const int*)d_in[3];
    const float* Wg = (const float*)d_in[4];
    const float* bg = (const float*)d_in[5];
    const float* W1 = (const float*)d_in[6];
    const float* b1 = (const float*)d_in[7];
    const float* W2 = (const float*)d_in[8];
    const float* b2 = (const float*)d_in[9];
    const float* W3 = (const float*)d_in[10];
    const float* b3 = (const float*)d_in[11];
    float* out = (float*)d_out;
    short* ws  = (short*)d_ws;
    short* ftH = (short*)((char*)d_ws + FT_OFF);
    short* ftL = ftH + FT_SHORTS;

    const int nxyz = kB * kP * 3;
    copy_newxyz<<<(nxyz + 255) / 256, 256, 0, stream>>>(new_xyz, out, nxyz);
    prep_weights<<<(53248 + 255) / 256, 256, 0, stream>>>(Wg, W1, W2, W3, ws);

    float* pooled = out + nxyz;
    if (ws_size >= WS_NEED) {
        prep_feat<<<kB * (kN / 64), 512, 0, stream>>>(features, ftH, ftL);
        pointnet_sa<true><<<(kB * kP * kS) / 64, 512, 0, stream>>>(
            xyz, features, new_xyz, idx, ws, ftH, ftL, bg, b1, b2, b3, pooled);
    } else {
        pointnet_sa<false><<<(kB * kP * kS) / 64, 512, 0, stream>>>(
            xyz, features, new_xyz, idx, ws, nullptr, nullptr, bg, b1, b2, b3, pooled);
    }
}